// Round 29
// baseline (471.753 us; speedup 1.0000x reference)
//
#include <hip/hip_runtime.h>
#include <cfloat>
#include <cmath>

#define NN 40000
#define DIN 3000
#define NE 640000
#define ET (NE + NN)   // edges incl. self-loops = 680000

#define NKS 94        // K-steps of 32 covering 3000 (94*32=3008, zero-padded B)
#define NKH 47        // K-steps per wave (in-block split-K x2)
#define NCT 192       // dec B-frag col tiles (192*16 = 3072 >= DIN)
#define NB_E 2657     // ceil(ET/256)
#define DCAP 64       // bucket capacity (Poisson(17) max over 40k ~ 36 << 64)

typedef __attribute__((ext_vector_type(8))) short short8;
typedef __attribute__((ext_vector_type(4))) float f32x4;

union frag16 { short8 s; uint4 u; };

__device__ __forceinline__ float lrelu(float x) { return x >= 0.f ? x : 0.2f * x; }
__device__ __forceinline__ float elu(float x)   { return x > 0.f ? x : expm1f(x); }
__device__ __forceinline__ unsigned f2bf(float f) {
    unsigned u = __float_as_uint(f);
    return (u + 0x7FFFu + ((u >> 16) & 1u)) >> 16;   // RNE fp32->bf16
}
__device__ __forceinline__ float bf2f(unsigned short us) {
    return __uint_as_float((unsigned)us << 16);
}

// ========== dispatch 1: weight-frag prep only (96 blocks, ~3 us) ==========
__global__ void k_wprep(const float* __restrict__ w, const float* __restrict__ ow,
                        unsigned short* __restrict__ bfw,
                        unsigned short* __restrict__ bfragb)
{
    int id = blockIdx.x * 256 + threadIdx.x;
    if (id < 96 * 128) {
        // enc0 B-fragment: kstep ks, col-tile t, lane l -> 8 bf16
        int ks = id >> 7, r = id & 127;
        int t = r >> 6, l = r & 63;
        int col = t * 16 + (l & 15);
        int k0 = ks * 32 + ((l >> 4) << 3);
        unsigned v[8];
        #pragma unroll
        for (int j = 0; j < 8; j++) {
            int k = k0 + j;
            v[j] = (k < DIN) ? f2bf(w[(size_t)k * 32 + col]) : 0u;
        }
        uint4 p;
        p.x = v[0] | (v[1] << 16); p.y = v[2] | (v[3] << 16);
        p.z = v[4] | (v[5] << 16); p.w = v[6] | (v[7] << 16);
        *(uint4*)&bfw[(size_t)id * 8] = p;
    } else {
        int tt = id - 96 * 128;
        if (tt < NCT * 64) {
            int ct = tt >> 6, l = tt & 63;
            int col = ct * 16 + (l & 15);
            int k0 = (l >> 4) * 8;
            uint4 p = make_uint4(0u, 0u, 0u, 0u);
            if (col < DIN) {
                unsigned v[8];
                #pragma unroll
                for (int j = 0; j < 8; j++)
                    v[j] = f2bf(ow[(size_t)(k0 + j) * DIN + col]);
                p.x = v[0] | (v[1] << 16); p.y = v[2] | (v[3] << 16);
                p.z = v[4] | (v[5] << 16); p.w = v[6] | (v[7] << 16);
            }
            *(uint4*)&bfragb[((size_t)ct * 64 + l) * 8] = p;
        }
    }
}

// ========== Kernel A (fused): bucket CSR fill (blocks [0,NB_E)) + enc0 MFMA + enc_prep ==========
// Fill blocks are short-lived/latency-bound and drain under the enc blocks'
// BW phase (enc does not depend on fill; gat1 launches after this kernel).
// Enc part: block = 2 waves, one 16-row group; split-K x2 MFMA; h stays in
// LDS; fx + hw1 + attn scalars computed in-block (see round-26 notes).
__global__ __launch_bounds__(128) void k_enc0_prep(
    const float* __restrict__ x, const unsigned short* __restrict__ bfw,
    const float* __restrict__ b, const float* __restrict__ g,
    const float* __restrict__ beta, const float* __restrict__ m,
    const float* __restrict__ v,
    const float* __restrict__ e1w, const float* __restrict__ e1b,
    const float* __restrict__ e1g, const float* __restrict__ e1beta,
    const float* __restrict__ e1m, const float* __restrict__ e1v,
    const float* __restrict__ g1w, const float* __restrict__ g1as,
    const float* __restrict__ g1ad,
    float* __restrict__ out_fx, unsigned short* __restrict__ hw1b,
    float* __restrict__ s1src, float* __restrict__ s1dst,
    const int* __restrict__ ei, int* __restrict__ cnt, int* __restrict__ srcs)
{
    const int tid = threadIdx.x;
    if (blockIdx.x < NB_E) {
        int e = blockIdx.x * 128 + (tid & 127);
        // two edges per thread to cover 256-wide stride with 128 threads
        #pragma unroll
        for (int half = 0; half < 2; half++) {
            int ee = blockIdx.x * 256 + half * 128 + tid;
            if (ee < ET) {
                int s, d;
                if (ee < NE) { s = ei[ee]; d = ei[NE + ee]; } else { s = d = ee - NE; }
                int pos = atomicAdd(&cnt[d], 1);
                if (pos < DCAP) srcs[((size_t)d << 6) + pos] = s;
            }
        }
        (void)e;
        return;
    }

    __shared__ float red[64 * 8];
    __shared__ float hs[16][33];
    __shared__ float fxs[16][20];
    const int wid = tid >> 6, l = tid & 63;
    const int gg = blockIdx.x - NB_E;            // row-group 0..2499
    const int row0 = gg * 16;
    const int row = row0 + (l & 15);
    const int klane = (l >> 4) << 3;

    const float* xp = x + (size_t)row * DIN + klane;
    const unsigned short* bp = bfw + (size_t)l * 8;

    f32x4 acc0 = {0.f, 0.f, 0.f, 0.f};
    f32x4 acc1 = {0.f, 0.f, 0.f, 0.f};

    const int ks0 = wid * NKH;
    #pragma unroll 4
    for (int ks = ks0; ks < ks0 + NKH; ks++) {
        frag16 a; a.u = make_uint4(0u, 0u, 0u, 0u);
        int k = ks * 32 + klane;
        if (k < DIN) {   // k mult of 8, k<=2992 -> reads k..k+7 in bounds
            float4 v0 = *(const float4*)(xp + ks * 32);
            float4 v1 = *(const float4*)(xp + ks * 32 + 4);
            a.u.x = f2bf(v0.x) | (f2bf(v0.y) << 16);
            a.u.y = f2bf(v0.z) | (f2bf(v0.w) << 16);
            a.u.z = f2bf(v1.x) | (f2bf(v1.y) << 16);
            a.u.w = f2bf(v1.z) | (f2bf(v1.w) << 16);
        }
        frag16 b0, b1;
        b0.u = *(const uint4*)(bp + (size_t)(ks * 2 + 0) * 512);
        b1.u = *(const uint4*)(bp + (size_t)(ks * 2 + 1) * 512);
        acc0 = __builtin_amdgcn_mfma_f32_16x16x32_bf16(a.s, b0.s, acc0, 0, 0, 0);
        acc1 = __builtin_amdgcn_mfma_f32_16x16x32_bf16(a.s, b1.s, acc1, 0, 0, 0);
    }

    if (wid == 1) {
        #pragma unroll
        for (int r = 0; r < 4; r++) {
            red[l * 8 + r]     = acc0[r];
            red[l * 8 + 4 + r] = acc1[r];
        }
    }
    __syncthreads();
    if (wid == 0) {
        #pragma unroll
        for (int r = 0; r < 4; r++) {
            acc0[r] += red[l * 8 + r];
            acc1[r] += red[l * 8 + 4 + r];
        }
        // BN + ELU -> h into LDS; D: col = l&15, row = (l>>4)*4 + reg
        const int cl = l & 15;
        const int rloc = (l >> 4) * 4;
        float sc0 = g[cl] * rsqrtf(v[cl] + 1e-3f);
        float sh0 = beta[cl] - m[cl] * sc0;
        float bb0 = b[cl];
        float sc1 = g[cl + 16] * rsqrtf(v[cl + 16] + 1e-3f);
        float sh1 = beta[cl + 16] - m[cl + 16] * sc1;
        float bb1 = b[cl + 16];
        #pragma unroll
        for (int reg = 0; reg < 4; reg++) {
            hs[rloc + reg][cl]      = elu((acc0[reg] + bb0) * sc0 + sh0);
            hs[rloc + reg][cl + 16] = elu((acc1[reg] + bb1) * sc1 + sh1);
        }
    }
    __syncthreads();

    // Phase 2: fx = elu(bn(h @ e1w + e1b)); 320 items over 128 threads
    for (int i = tid; i < 320; i += 128) {
        int r = i / 20, c = i - r * 20;
        float s = e1b[c];
        #pragma unroll
        for (int k = 0; k < 32; k++) s += hs[r][k] * e1w[k * 20 + c];
        float sc = e1g[c] * rsqrtf(e1v[c] + 1e-3f);
        s = (s - e1m[c]) * sc + e1beta[c];
        float fx = elu(s);
        fxs[r][c] = fx;
        out_fx[(size_t)(row0 + r) * 20 + c] = fx;
    }
    __syncthreads();

    // Phase 3: hw1 = fx @ g1w; 8 iters, wave = row (2j+wid), lane = col
    #pragma unroll
    for (int j = 0; j < 8; j++) {
        const int rl = 2 * j + wid;
        float s = 0.f;
        #pragma unroll
        for (int k = 0; k < 20; k++) s += fxs[rl][k] * g1w[k * 64 + l];
        hw1b[(size_t)(row0 + rl) * 64 + l] = (unsigned short)f2bf(s);
        float u1 = s * g1as[l];
        float u2 = s * g1ad[l];
        u1 += __shfl_xor(u1, 1); u1 += __shfl_xor(u1, 2); u1 += __shfl_xor(u1, 4);
        u1 += __shfl_xor(u1, 8); u1 += __shfl_xor(u1, 16); u1 += __shfl_xor(u1, 32);
        u2 += __shfl_xor(u2, 1); u2 += __shfl_xor(u2, 2); u2 += __shfl_xor(u2, 4);
        u2 += __shfl_xor(u2, 8); u2 += __shfl_xor(u2, 16); u2 += __shfl_xor(u2, 32);
        if (l == 0) { s1src[row0 + rl] = u1; s1dst[row0 + rl] = u2; }
    }
}

// ------------- GAT1 gather+norm (fused): one wave per dst, 64 lanes = features -------------
__global__ __launch_bounds__(256) void k_gat1_fused(
    const int* __restrict__ cnt, const int* __restrict__ srcs,
    const float* __restrict__ s1src, const float* __restrict__ s1dst,
    const unsigned short* __restrict__ hw1b,
    const float* __restrict__ g1b,
    const float* __restrict__ bncg, const float* __restrict__ bncbeta,
    const float* __restrict__ bncm, const float* __restrict__ bncv,
    const float* __restrict__ gmw, const float* __restrict__ gmas, const float* __restrict__ gmad,
    const float* __restrict__ gvw, const float* __restrict__ gvas, const float* __restrict__ gvad,
    float* __restrict__ hwmv, float* __restrict__ sv4)
{
    __shared__ float cs[4][64];
    const int wv = threadIdx.x >> 6;
    int d = (blockIdx.x * 256 + threadIdx.x) >> 6;
    int l = threadIdx.x & 63;
    if (d >= NN) return;
    const int j0 = d << 6;                     // bucket base (no dependent load)
    int n = cnt[d]; n = (n < DCAP) ? n : DCAP;
    float sd = s1dst[d];
    float acc = 0.f, z = 0.f;
    int j = 0;
    for (; j + 4 <= n; j += 4) {
        int s0 = srcs[j0 + j], s1 = srcs[j0 + j + 1];
        int s2 = srcs[j0 + j + 2], s3 = srcs[j0 + j + 3];
        float a0 = s1src[s0], a1 = s1src[s1], a2 = s1src[s2], a3 = s1src[s3];
        float h0 = bf2f(hw1b[(size_t)s0 * 64 + l]);
        float h1 = bf2f(hw1b[(size_t)s1 * 64 + l]);
        float h2 = bf2f(hw1b[(size_t)s2 * 64 + l]);
        float h3 = bf2f(hw1b[(size_t)s3 * 64 + l]);
        float e0 = expf(lrelu(a0 + sd)), e1 = expf(lrelu(a1 + sd));
        float e2 = expf(lrelu(a2 + sd)), e3 = expf(lrelu(a3 + sd));
        z += (e0 + e1) + (e2 + e3);
        acc += e0 * h0; acc += e1 * h1; acc += e2 * h2; acc += e3 * h3;
    }
    for (; j < n; j++) {
        int s = srcs[j0 + j];
        float ex = expf(lrelu(s1src[s] + sd));
        z += ex;
        acc += ex * bf2f(hw1b[(size_t)s * 64 + l]);
    }
    // normalize + BN + ReLU per lane (feature l)
    float zi = 1.f / (z + 1e-16f);
    float val = acc * zi + g1b[l];
    float sc = bncg[l] * rsqrtf(bncv[l] + 1e-5f);
    val = (val - bncm[l]) * sc + bncbeta[l];
    float c = val > 0.f ? val : 0.f;
    cs[wv][l] = c;          // wave-private LDS; same-wave in-order -> no barrier

    if (l < 16) {
        const bool isv = l >= 8;
        const int o = l & 7;
        const float* wmat = isv ? gvw : gmw;
        float s = 0.f;
        #pragma unroll 8
        for (int k = 0; k < 64; k++)
            s += cs[wv][k] * wmat[k * 8 + o];    // cs broadcast read
        hwmv[(size_t)d * 16 + l] = s;            // contiguous 64B line (m||v)
        float u1 = s * (isv ? gvas[o] : gmas[o]);
        float u2 = s * (isv ? gvad[o] : gmad[o]);
        u1 += __shfl_xor(u1, 1); u1 += __shfl_xor(u1, 2); u1 += __shfl_xor(u1, 4);
        u2 += __shfl_xor(u2, 1); u2 += __shfl_xor(u2, 2); u2 += __shfl_xor(u2, 4);
        if (o == 0) {
            if (!isv) { sv4[(size_t)d * 4 + 0] = u1; sv4[(size_t)d * 4 + 1] = u2; }
            else      { sv4[(size_t)d * 4 + 2] = u1; sv4[(size_t)d * 4 + 3] = u2; }
        }
    }
}

// ------------- GAT2/3 gather + FINAL (fused): one wave per dst -------------
__global__ __launch_bounds__(256) void k_gat23_final(
    const int* __restrict__ cnt, const int* __restrict__ srcs,
    const float* __restrict__ hwmv, const float* __restrict__ sv4,
    const float* __restrict__ gmb, const float* __restrict__ gvb,
    const float* __restrict__ epsin, const float* __restrict__ fx_out,
    const float* __restrict__ d0w, const float* __restrict__ d0b,
    const float* __restrict__ d0g, const float* __restrict__ d0beta,
    const float* __restrict__ d0m, const float* __restrict__ d0v,
    const float* __restrict__ cluster,
    float* __restrict__ out_z, float* __restrict__ out_mu, float* __restrict__ out_lv,
    float* __restrict__ out_q, float* __restrict__ out_gz,
    unsigned short* __restrict__ abuf)
{
    __shared__ float zs[4][28];
    __shared__ float dvs[4][32];
    const int wv = threadIdx.x >> 6;
    int d = (blockIdx.x * 256 + threadIdx.x) >> 6;
    int l = threadIdx.x & 63;
    if (d >= NN) return;
    const int eg = l >> 4;
    const bool isv = (l & 15) >= 8;
    const int f = l & 7;
    const int fmv = l & 15;                 // 0..7 m, 8..15 v (hwmv offset)
    const int j0 = d << 6;
    int n = cnt[d]; n = (n < DCAP) ? n : DCAP;
    float sdst = sv4[(size_t)d * 4 + (isv ? 3 : 1)];
    float acc = 0.f, z = 0.f;
    for (int j = eg; j < n; j += 4) {
        int s = srcs[j0 + j];
        float a = sv4[(size_t)s * 4 + (isv ? 2 : 0)] + sdst;
        float ex = expf(lrelu(a));
        z += ex;
        acc += ex * hwmv[(size_t)s * 16 + fmv];
    }
    acc += __shfl_xor(acc, 16); acc += __shfl_xor(acc, 32);
    z   += __shfl_xor(z, 16);   z   += __shfl_xor(z, 32);
    // every lane: acc = accm[f] (m-lanes) or accv[f] (v-lanes); z = zm or zv
    float zi = 1.f / (z + 1e-16f);
    float t = acc * zi + (isv ? gvb[f] : gmb[f]);   // mu on m-lanes, lv on v-lanes
    float partner = __shfl_xor(t, 8);               // m-lane gets lv
    float gz = 0.f;
    if (l < 8) gz = epsin[(size_t)d * 8 + f] * expf(partner) + t;
    if (l < 8)        { out_mu[(size_t)d * 8 + f] = t; out_gz[(size_t)d * 8 + f] = gz; }
    else if (l < 16)  { out_lv[(size_t)d * 8 + f] = t; }
    // zvec -> wave LDS (fx 0..19, gnn_z 20..27); same-wave in-order, no barrier
    if (l < 20) zs[wv][l] = fx_out[(size_t)d * 20 + l];
    if (l < 8)  zs[wv][20 + l] = gz;
    if (l < 28) out_z[(size_t)d * 28 + l] = zs[wv][l];
    // decoder L0: lane c computes dv[c]
    if (l < 32) {
        float s = d0b[l];
        #pragma unroll
        for (int k = 0; k < 28; k++) s += zs[wv][k] * d0w[k * 32 + l];
        float sc = d0g[l] * rsqrtf(d0v[l] + 1e-3f);
        s = (s - d0m[l]) * sc + d0beta[l];
        dvs[wv][l] = elu(s);
    }
    // abuf A-frag pack: lanes 0..3 = hh
    if (l < 4) {
        int g = d >> 4, rl = d & 15;
        const float* dv = dvs[wv];
        uint4 p;
        p.x = f2bf(dv[l*8+0]) | (f2bf(dv[l*8+1]) << 16);
        p.y = f2bf(dv[l*8+2]) | (f2bf(dv[l*8+3]) << 16);
        p.z = f2bf(dv[l*8+4]) | (f2bf(dv[l*8+5]) << 16);
        p.w = f2bf(dv[l*8+6]) | (f2bf(dv[l*8+7]) << 16);
        *(uint4*)&abuf[(size_t)g * 512 + (rl + 16 * l) * 8] = p;
    }
    // student-t q: lane j<15 computes cluster j; reduce qs in 16-lane group
    float zz = 0.f;
    #pragma unroll
    for (int k = 0; k < 28; k++) { float zk = zs[wv][k]; zz += zk * zk; }
    float qb = 0.f;
    if (l < 15) {
        float cc = 0.f, zc = 0.f;
        #pragma unroll
        for (int k = 0; k < 28; k++) {
            float cv = cluster[l * 28 + k];
            cc += cv * cv; zc += zs[wv][k] * cv;
        }
        float sq = zz + cc - 2.f * zc;
        if (sq < 0.f) sq = 0.f;
        qb = 1.f / (1.f + sq * (1.f / 0.9f) + 1e-8f);
        qb = powf(qb, 0.95f);
    }
    float qs = qb;
    qs += __shfl_xor(qs, 1); qs += __shfl_xor(qs, 2);
    qs += __shfl_xor(qs, 4); qs += __shfl_xor(qs, 8);
    if (l < 15) out_q[(size_t)d * 15 + l] = qb / qs;
}

// ------------- Kernel I: de_feat = d @ out_w + out_b, MFMA + LDS-staged NT-store epilogue -------------
#define OTS 132   // LDS row stride (132*4B % 16 == 0 -> aligned b128; 2-way write alias = free)
__global__ __launch_bounds__(256) void k_dec_out(
    const unsigned short* __restrict__ abuf, const unsigned short* __restrict__ bfragb,
    const float* __restrict__ ob, float* __restrict__ out_de)
{
    __shared__ float ot[64 * OTS];   // 33.8 KB
    const int tid = threadIdx.x, wid = tid >> 6, l = tid & 63;
    const int gblk = blockIdx.y;               // 64-row block 0..624
    const int ct0 = blockIdx.x * 8;
    frag16 a; a.u = *(const uint4*)&abuf[((size_t)(gblk * 4 + wid)) * 512 + l * 8];
    const int lrow = wid * 16 + (l >> 4) * 4;  // local row base
    const int cl = l & 15;
    #pragma unroll
    for (int c = 0; c < 8; c++) {
        frag16 bfr; bfr.u = *(const uint4*)&bfragb[((size_t)(ct0 + c) * 64 + l) * 8];
        f32x4 acc = {0.f, 0.f, 0.f, 0.f};
        acc = __builtin_amdgcn_mfma_f32_16x16x32_bf16(a.s, bfr.s, acc, 0, 0, 0);
        #pragma unroll
        for (int reg = 0; reg < 4; reg++)
            ot[(lrow + reg) * OTS + c * 16 + cl] = acc[reg];
    }
    __syncthreads();
    const int row0 = gblk * 64;
    const int c0 = ct0 * 16;
    #pragma unroll
    for (int i = 0; i < 8; i++) {
        int idx = i * 256 + tid;
        int r = idx >> 5, q = idx & 31;
        int col = c0 + q * 4;
        if (col < DIN) {
            const float* p = &ot[r * OTS + q * 4];
            float4 bq = *(const float4*)&ob[col];
            f32x4 o;
            o[0] = p[0] + bq.x; o[1] = p[1] + bq.y;
            o[2] = p[2] + bq.z; o[3] = p[3] + bq.w;
            __builtin_nontemporal_store(o, (f32x4*)&out_de[(size_t)(row0 + r) * DIN + col]);
        }
    }
}

extern "C" void kernel_launch(void* const* d_in, const int* in_sizes, int n_in,
                              void* d_out, int out_size, void* d_ws, size_t ws_size,
                              hipStream_t stream) {
    const float* x      = (const float*)d_in[0];
    const int*   ei     = (const int*)  d_in[1];
    const float* e0_w   = (const float*)d_in[2];
    const float* e0_b   = (const float*)d_in[3];
    const float* e0_g   = (const float*)d_in[4];
    const float* e0_be  = (const float*)d_in[5];
    const float* e0_m   = (const float*)d_in[6];
    const float* e0_v   = (const float*)d_in[7];
    const float* e1_w   = (const float*)d_in[8];
    const float* e1_b   = (const float*)d_in[9];
    const float* e1_g   = (const float*)d_in[10];
    const float* e1_be  = (const float*)d_in[11];
    const float* e1_m   = (const float*)d_in[12];
    const float* e1_v   = (const float*)d_in[13];
    const float* g1_w   = (const float*)d_in[14];
    const float* g1_as  = (const float*)d_in[15];
    const float* g1_ad  = (const float*)d_in[16];
    const float* g1_b   = (const float*)d_in[17];
    const float* bnc_g  = (const float*)d_in[18];
    const float* bnc_be = (const float*)d_in[19];
    const float* bnc_m  = (const float*)d_in[20];
    const float* bnc_v  = (const float*)d_in[21];
    const float* gm_w   = (const float*)d_in[22];
    const float* gm_as  = (const float*)d_in[23];
    const float* gm_ad  = (const float*)d_in[24];
    const float* gm_b   = (const float*)d_in[25];
    const float* gv_w   = (const float*)d_in[26];
    const float* gv_as  = (const float*)d_in[27];
    const float* gv_ad  = (const float*)d_in[28];
    const float* gv_b   = (const float*)d_in[29];
    const float* d0_w   = (const float*)d_in[30];
    const float* d0_b   = (const float*)d_in[31];
    const float* d0_g   = (const float*)d_in[32];
    const float* d0_be  = (const float*)d_in[33];
    const float* d0_m   = (const float*)d_in[34];
    const float* d0_v   = (const float*)d_in[35];
    const float* out_w  = (const float*)d_in[36];
    const float* out_b  = (const float*)d_in[37];
    const float* cluster= (const float*)d_in[38];
    const float* epsin  = (const float*)d_in[39];

    float* out = (float*)d_out;
    // output offsets (floats), return order: z, mu, logvar, de_feat, q, feat_x, gnn_z
    float* out_z  = out;
    float* out_mu = out + (size_t)NN * 28;
    float* out_lv = out + (size_t)NN * 36;
    float* out_de = out + (size_t)NN * 44;
    float* out_q  = out + (size_t)NN * 44 + (size_t)NN * DIN;
    float* out_fx = out + (size_t)NN * 59 + (size_t)NN * DIN;
    float* out_gz = out + (size_t)NN * 79 + (size_t)NN * DIN;

    float* ws = (float*)d_ws;
    const size_t n = NN;
    // workspace layout
    unsigned short* hw1b = (unsigned short*)(ws + 64 * n);   // NN*64 bf16 = 64N..96N
    float* s1src   = ws + 96 * n;
    float* s1dst   = ws + 97 * n;
    unsigned short* abuf   = (unsigned short*)(ws + 103 * n);   // NN*32 bf16 = 103N..119N
    unsigned short* bfw    = (unsigned short*)(ws + 119 * n);   // 96*2*512 bf16 (192KB)
    unsigned short* bfragb = (unsigned short*)(ws + 121 * n);   // NCT*64*8 bf16 (192KB)
    // phase-2 (GAT) interleaved buffers (live in region dead during GAT phase)
    float* hwmv = ws;                          // [NN][16] = 0..16N
    float* sv4  = ws + 16 * n;                 // [NN][4]  = 16N..20N

    // bucket CSR lives in the de_feat output region (overwritten last by k_dec_out)
    int* srcs = (int*)out_de;          // NN*64 = 10.24 MB
    int* cnt  = srcs + (size_t)NN * DCAP;  // NN

    const int NB_PREP = (96 * 128 + NCT * 64 + 255) / 256;  // 96

    // weight prep (tiny) + cnt zeroing
    (void)hipMemsetAsync(cnt, 0, NN * sizeof(int), stream);
    k_wprep<<<NB_PREP, 256, 0, stream>>>(e0_w, out_w, bfw, bfragb);

    // bucket fill (blocks [0,NB_E)) + encoder GEMM/prep (blocks >= NB_E) in ONE launch:
    // fill is latency-bound and drains under enc's BW phase; gat1 waits on both.
    k_enc0_prep<<<NB_E + NN / 16, 128, 0, stream>>>(x, bfw, e0_b, e0_g, e0_be, e0_m, e0_v,
                                                    e1_w, e1_b, e1_g, e1_be, e1_m, e1_v,
                                                    g1_w, g1_as, g1_ad,
                                                    out_fx, hw1b, s1src, s1dst,
                                                    ei, cnt, srcs);
    // GAT1 gather + norm fused (interleaved outputs)
    k_gat1_fused<<<(NN * 64 + 255) / 256, 256, 0, stream>>>(cnt, srcs,
                                                            s1src, s1dst, hw1b,
                                                            g1_b, bnc_g, bnc_be, bnc_m, bnc_v,
                                                            gm_w, gm_as, gm_ad,
                                                            gv_w, gv_as, gv_ad,
                                                            hwmv, sv4);
    // GAT mu/logvar gather + final fused (interleaved gathers)
    k_gat23_final<<<(NN * 64 + 255) / 256, 256, 0, stream>>>(cnt, srcs,
                                                             hwmv, sv4,
                                                             gm_b, gv_b, epsin, out_fx,
                                                             d0_w, d0_b, d0_g, d0_be, d0_m, d0_v,
                                                             cluster,
                                                             out_z, out_mu, out_lv, out_q, out_gz,
                                                             abuf);
    // decoder out (MFMA + coalesced NT-store epilogue)
    dim3 dec_grid(NCT / 8, NN / 64);   // 24 x 625
    k_dec_out<<<dec_grid, 256, 0, stream>>>(abuf, bfragb, out_b, out_de);
}

// Round 30
// 433.004 us; speedup vs baseline: 1.0895x; 1.0895x over previous
//
#include <hip/hip_runtime.h>
#include <cfloat>
#include <cmath>

#define NN 40000
#define DIN 3000
#define NE 640000
#define ET (NE + NN)   // edges incl. self-loops = 680000

#define NKS 94        // K-steps of 32 covering 3000 (94*32=3008, zero-padded B)
#define NKH 47        // K-steps per wave (in-block split-K x2)
#define NCT 192       // dec B-frag col tiles (192*16 = 3072 >= DIN)
#define NB_E 2657     // ceil(ET/256)
#define DCAP 64       // bucket capacity (Poisson(17) max over 40k ~ 36 << 64)

typedef __attribute__((ext_vector_type(8))) short short8;
typedef __attribute__((ext_vector_type(4))) float f32x4;

union frag16 { short8 s; uint4 u; };

__device__ __forceinline__ float lrelu(float x) { return x >= 0.f ? x : 0.2f * x; }
__device__ __forceinline__ float elu(float x)   { return x > 0.f ? x : expm1f(x); }
__device__ __forceinline__ unsigned f2bf(float f) {
    unsigned u = __float_as_uint(f);
    return (u + 0x7FFFu + ((u >> 16) & 1u)) >> 16;   // RNE fp32->bf16
}
__device__ __forceinline__ float bf2f(unsigned short us) {
    return __uint_as_float((unsigned)us << 16);
}

// ========== merged: bucket CSR fill (1 edge pass, no scan) + weight-frag prep ==========
__global__ void k_fill_prep(const int* __restrict__ ei, int* __restrict__ cnt,
                            int* __restrict__ srcs,
                            const float* __restrict__ w, const float* __restrict__ ow,
                            unsigned short* __restrict__ bfw,
                            unsigned short* __restrict__ bfragb)
{
    if (blockIdx.x < NB_E) {
        int e = blockIdx.x * 256 + threadIdx.x;
        if (e >= ET) return;
        int s, d;
        if (e < NE) { s = ei[e]; d = ei[NE + e]; } else { s = d = e - NE; }
        int pos = atomicAdd(&cnt[d], 1);
        if (pos < DCAP) srcs[((size_t)d << 6) + pos] = s;
    } else {
        int id = (blockIdx.x - NB_E) * 256 + threadIdx.x;
        if (id < 96 * 128) {
            // enc0 B-fragment: kstep ks, col-tile t, lane l -> 8 bf16
            int ks = id >> 7, r = id & 127;
            int t = r >> 6, l = r & 63;
            int col = t * 16 + (l & 15);
            int k0 = ks * 32 + ((l >> 4) << 3);
            unsigned v[8];
            #pragma unroll
            for (int j = 0; j < 8; j++) {
                int k = k0 + j;
                v[j] = (k < DIN) ? f2bf(w[(size_t)k * 32 + col]) : 0u;
            }
            uint4 p;
            p.x = v[0] | (v[1] << 16); p.y = v[2] | (v[3] << 16);
            p.z = v[4] | (v[5] << 16); p.w = v[6] | (v[7] << 16);
            *(uint4*)&bfw[(size_t)id * 8] = p;
        } else {
            int tt = id - 96 * 128;
            if (tt < NCT * 64) {
                int ct = tt >> 6, l = tt & 63;
                int col = ct * 16 + (l & 15);
                int k0 = (l >> 4) * 8;
                uint4 p = make_uint4(0u, 0u, 0u, 0u);
                if (col < DIN) {
                    unsigned v[8];
                    #pragma unroll
                    for (int j = 0; j < 8; j++)
                        v[j] = f2bf(ow[(size_t)(k0 + j) * DIN + col]);
                    p.x = v[0] | (v[1] << 16); p.y = v[2] | (v[3] << 16);
                    p.z = v[4] | (v[5] << 16); p.w = v[6] | (v[7] << 16);
                }
                *(uint4*)&bfragb[((size_t)ct * 64 + l) * 8] = p;
            }
        }
    }
}

// ========== Kernel A (fused): enc0 MFMA + enc_prep, h never leaves the block ==========
__global__ __launch_bounds__(128) void k_enc0_prep(
    const float* __restrict__ x, const unsigned short* __restrict__ bfw,
    const float* __restrict__ b, const float* __restrict__ g,
    const float* __restrict__ beta, const float* __restrict__ m,
    const float* __restrict__ v,
    const float* __restrict__ e1w, const float* __restrict__ e1b,
    const float* __restrict__ e1g, const float* __restrict__ e1beta,
    const float* __restrict__ e1m, const float* __restrict__ e1v,
    const float* __restrict__ g1w, const float* __restrict__ g1as,
    const float* __restrict__ g1ad,
    float* __restrict__ out_fx, unsigned short* __restrict__ hw1b,
    float* __restrict__ s1src, float* __restrict__ s1dst)
{
    __shared__ float red[64 * 8];
    __shared__ float hs[16][33];
    __shared__ float fxs[16][20];
    const int tid = threadIdx.x, wid = tid >> 6, l = tid & 63;
    const int gg = blockIdx.x;                   // row-group 0..2499
    const int row0 = gg * 16;
    const int row = row0 + (l & 15);
    const int klane = (l >> 4) << 3;

    const float* xp = x + (size_t)row * DIN + klane;
    const unsigned short* bp = bfw + (size_t)l * 8;

    f32x4 acc0 = {0.f, 0.f, 0.f, 0.f};
    f32x4 acc1 = {0.f, 0.f, 0.f, 0.f};

    const int ks0 = wid * NKH;
    #pragma unroll 4
    for (int ks = ks0; ks < ks0 + NKH; ks++) {
        frag16 a; a.u = make_uint4(0u, 0u, 0u, 0u);
        int k = ks * 32 + klane;
        if (k < DIN) {   // k mult of 8, k<=2992 -> reads k..k+7 in bounds
            float4 v0 = *(const float4*)(xp + ks * 32);
            float4 v1 = *(const float4*)(xp + ks * 32 + 4);
            a.u.x = f2bf(v0.x) | (f2bf(v0.y) << 16);
            a.u.y = f2bf(v0.z) | (f2bf(v0.w) << 16);
            a.u.z = f2bf(v1.x) | (f2bf(v1.y) << 16);
            a.u.w = f2bf(v1.z) | (f2bf(v1.w) << 16);
        }
        frag16 b0, b1;
        b0.u = *(const uint4*)(bp + (size_t)(ks * 2 + 0) * 512);
        b1.u = *(const uint4*)(bp + (size_t)(ks * 2 + 1) * 512);
        acc0 = __builtin_amdgcn_mfma_f32_16x16x32_bf16(a.s, b0.s, acc0, 0, 0, 0);
        acc1 = __builtin_amdgcn_mfma_f32_16x16x32_bf16(a.s, b1.s, acc1, 0, 0, 0);
    }

    if (wid == 1) {
        #pragma unroll
        for (int r = 0; r < 4; r++) {
            red[l * 8 + r]     = acc0[r];
            red[l * 8 + 4 + r] = acc1[r];
        }
    }
    __syncthreads();
    if (wid == 0) {
        #pragma unroll
        for (int r = 0; r < 4; r++) {
            acc0[r] += red[l * 8 + r];
            acc1[r] += red[l * 8 + 4 + r];
        }
        // BN + ELU -> h into LDS; D: col = l&15, row = (l>>4)*4 + reg
        const int cl = l & 15;
        const int rloc = (l >> 4) * 4;
        float sc0 = g[cl] * rsqrtf(v[cl] + 1e-3f);
        float sh0 = beta[cl] - m[cl] * sc0;
        float bb0 = b[cl];
        float sc1 = g[cl + 16] * rsqrtf(v[cl + 16] + 1e-3f);
        float sh1 = beta[cl + 16] - m[cl + 16] * sc1;
        float bb1 = b[cl + 16];
        #pragma unroll
        for (int reg = 0; reg < 4; reg++) {
            hs[rloc + reg][cl]      = elu((acc0[reg] + bb0) * sc0 + sh0);
            hs[rloc + reg][cl + 16] = elu((acc1[reg] + bb1) * sc1 + sh1);
        }
    }
    __syncthreads();

    // Phase 2: fx = elu(bn(h @ e1w + e1b)); 320 items over 128 threads
    for (int i = tid; i < 320; i += 128) {
        int r = i / 20, c = i - r * 20;
        float s = e1b[c];
        #pragma unroll
        for (int k = 0; k < 32; k++) s += hs[r][k] * e1w[k * 20 + c];
        float sc = e1g[c] * rsqrtf(e1v[c] + 1e-3f);
        s = (s - e1m[c]) * sc + e1beta[c];
        float fx = elu(s);
        fxs[r][c] = fx;
        out_fx[(size_t)(row0 + r) * 20 + c] = fx;
    }
    __syncthreads();

    // Phase 3: hw1 = fx @ g1w; 8 iters, wave = row (2j+wid), lane = col
    #pragma unroll
    for (int j = 0; j < 8; j++) {
        const int rl = 2 * j + wid;
        float s = 0.f;
        #pragma unroll
        for (int k = 0; k < 20; k++) s += fxs[rl][k] * g1w[k * 64 + l];
        hw1b[(size_t)(row0 + rl) * 64 + l] = (unsigned short)f2bf(s);
        float u1 = s * g1as[l];
        float u2 = s * g1ad[l];
        u1 += __shfl_xor(u1, 1); u1 += __shfl_xor(u1, 2); u1 += __shfl_xor(u1, 4);
        u1 += __shfl_xor(u1, 8); u1 += __shfl_xor(u1, 16); u1 += __shfl_xor(u1, 32);
        u2 += __shfl_xor(u2, 1); u2 += __shfl_xor(u2, 2); u2 += __shfl_xor(u2, 4);
        u2 += __shfl_xor(u2, 8); u2 += __shfl_xor(u2, 16); u2 += __shfl_xor(u2, 32);
        if (l == 0) { s1src[row0 + rl] = u1; s1dst[row0 + rl] = u2; }
    }
}

// ------------- GAT1 gather+norm (fused): one wave per dst, 64 lanes = features -------------
// Writes interleaved hwmv[d][16] (m||v, one 64B line) and sv4[d] = {smsrc,
// smdst, svsrc, svdst} (one 16B line) so gat23's random gather touches 2
// cache lines per source instead of 4.
__global__ __launch_bounds__(256) void k_gat1_fused(
    const int* __restrict__ cnt, const int* __restrict__ srcs,
    const float* __restrict__ s1src, const float* __restrict__ s1dst,
    const unsigned short* __restrict__ hw1b,
    const float* __restrict__ g1b,
    const float* __restrict__ bncg, const float* __restrict__ bncbeta,
    const float* __restrict__ bncm, const float* __restrict__ bncv,
    const float* __restrict__ gmw, const float* __restrict__ gmas, const float* __restrict__ gmad,
    const float* __restrict__ gvw, const float* __restrict__ gvas, const float* __restrict__ gvad,
    float* __restrict__ hwmv, float* __restrict__ sv4)
{
    __shared__ float cs[4][64];
    const int wv = threadIdx.x >> 6;
    int d = (blockIdx.x * 256 + threadIdx.x) >> 6;
    int l = threadIdx.x & 63;
    if (d >= NN) return;
    const int j0 = d << 6;                     // bucket base (no dependent load)
    int n = cnt[d]; n = (n < DCAP) ? n : DCAP;
    float sd = s1dst[d];
    float acc = 0.f, z = 0.f;
    int j = 0;
    for (; j + 4 <= n; j += 4) {
        int s0 = srcs[j0 + j], s1 = srcs[j0 + j + 1];
        int s2 = srcs[j0 + j + 2], s3 = srcs[j0 + j + 3];
        float a0 = s1src[s0], a1 = s1src[s1], a2 = s1src[s2], a3 = s1src[s3];
        float h0 = bf2f(hw1b[(size_t)s0 * 64 + l]);
        float h1 = bf2f(hw1b[(size_t)s1 * 64 + l]);
        float h2 = bf2f(hw1b[(size_t)s2 * 64 + l]);
        float h3 = bf2f(hw1b[(size_t)s3 * 64 + l]);
        float e0 = expf(lrelu(a0 + sd)), e1 = expf(lrelu(a1 + sd));
        float e2 = expf(lrelu(a2 + sd)), e3 = expf(lrelu(a3 + sd));
        z += (e0 + e1) + (e2 + e3);
        acc += e0 * h0; acc += e1 * h1; acc += e2 * h2; acc += e3 * h3;
    }
    for (; j < n; j++) {
        int s = srcs[j0 + j];
        float ex = expf(lrelu(s1src[s] + sd));
        z += ex;
        acc += ex * bf2f(hw1b[(size_t)s * 64 + l]);
    }
    // normalize + BN + ReLU per lane (feature l)
    float zi = 1.f / (z + 1e-16f);
    float val = acc * zi + g1b[l];
    float sc = bncg[l] * rsqrtf(bncv[l] + 1e-5f);
    val = (val - bncm[l]) * sc + bncbeta[l];
    float c = val > 0.f ? val : 0.f;
    cs[wv][l] = c;          // wave-private LDS; same-wave in-order -> no barrier

    if (l < 16) {
        const bool isv = l >= 8;
        const int o = l & 7;
        const float* wmat = isv ? gvw : gmw;
        float s = 0.f;
        #pragma unroll 8
        for (int k = 0; k < 64; k++)
            s += cs[wv][k] * wmat[k * 8 + o];    // cs broadcast read
        hwmv[(size_t)d * 16 + l] = s;            // contiguous 64B line (m||v)
        float u1 = s * (isv ? gvas[o] : gmas[o]);
        float u2 = s * (isv ? gvad[o] : gmad[o]);
        u1 += __shfl_xor(u1, 1); u1 += __shfl_xor(u1, 2); u1 += __shfl_xor(u1, 4);
        u2 += __shfl_xor(u2, 1); u2 += __shfl_xor(u2, 2); u2 += __shfl_xor(u2, 4);
        if (o == 0) {
            if (!isv) { sv4[(size_t)d * 4 + 0] = u1; sv4[(size_t)d * 4 + 1] = u2; }
            else      { sv4[(size_t)d * 4 + 2] = u1; sv4[(size_t)d * 4 + 3] = u2; }
        }
    }
}

// ------------- GAT2/3 gather + FINAL (fused): one wave per dst -------------
// Interleaved gathers: per edge, one 16B sv4 line + one 64B hwmv line.
__global__ __launch_bounds__(256) void k_gat23_final(
    const int* __restrict__ cnt, const int* __restrict__ srcs,
    const float* __restrict__ hwmv, const float* __restrict__ sv4,
    const float* __restrict__ gmb, const float* __restrict__ gvb,
    const float* __restrict__ epsin, const float* __restrict__ fx_out,
    const float* __restrict__ d0w, const float* __restrict__ d0b,
    const float* __restrict__ d0g, const float* __restrict__ d0beta,
    const float* __restrict__ d0m, const float* __restrict__ d0v,
    const float* __restrict__ cluster,
    float* __restrict__ out_z, float* __restrict__ out_mu, float* __restrict__ out_lv,
    float* __restrict__ out_q, float* __restrict__ out_gz,
    unsigned short* __restrict__ abuf)
{
    __shared__ float zs[4][28];
    __shared__ float dvs[4][32];
    const int wv = threadIdx.x >> 6;
    int d = (blockIdx.x * 256 + threadIdx.x) >> 6;
    int l = threadIdx.x & 63;
    if (d >= NN) return;
    const int eg = l >> 4;
    const bool isv = (l & 15) >= 8;
    const int f = l & 7;
    const int fmv = l & 15;                 // 0..7 m, 8..15 v (hwmv offset)
    const int j0 = d << 6;
    int n = cnt[d]; n = (n < DCAP) ? n : DCAP;
    float sdst = sv4[(size_t)d * 4 + (isv ? 3 : 1)];
    float acc = 0.f, z = 0.f;
    for (int j = eg; j < n; j += 4) {
        int s = srcs[j0 + j];
        float a = sv4[(size_t)s * 4 + (isv ? 2 : 0)] + sdst;
        float ex = expf(lrelu(a));
        z += ex;
        acc += ex * hwmv[(size_t)s * 16 + fmv];
    }
    acc += __shfl_xor(acc, 16); acc += __shfl_xor(acc, 32);
    z   += __shfl_xor(z, 16);   z   += __shfl_xor(z, 32);
    // every lane: acc = accm[f] (m-lanes) or accv[f] (v-lanes); z = zm or zv
    float zi = 1.f / (z + 1e-16f);
    float t = acc * zi + (isv ? gvb[f] : gmb[f]);   // mu on m-lanes, lv on v-lanes
    float partner = __shfl_xor(t, 8);               // m-lane gets lv
    float gz = 0.f;
    if (l < 8) gz = epsin[(size_t)d * 8 + f] * expf(partner) + t;
    if (l < 8)        { out_mu[(size_t)d * 8 + f] = t; out_gz[(size_t)d * 8 + f] = gz; }
    else if (l < 16)  { out_lv[(size_t)d * 8 + f] = t; }
    // zvec -> wave LDS (fx 0..19, gnn_z 20..27); same-wave in-order, no barrier
    if (l < 20) zs[wv][l] = fx_out[(size_t)d * 20 + l];
    if (l < 8)  zs[wv][20 + l] = gz;
    if (l < 28) out_z[(size_t)d * 28 + l] = zs[wv][l];
    // decoder L0: lane c computes dv[c]
    if (l < 32) {
        float s = d0b[l];
        #pragma unroll
        for (int k = 0; k < 28; k++) s += zs[wv][k] * d0w[k * 32 + l];
        float sc = d0g[l] * rsqrtf(d0v[l] + 1e-3f);
        s = (s - d0m[l]) * sc + d0beta[l];
        dvs[wv][l] = elu(s);
    }
    // abuf A-frag pack: lanes 0..3 = hh
    if (l < 4) {
        int g = d >> 4, rl = d & 15;
        const float* dv = dvs[wv];
        uint4 p;
        p.x = f2bf(dv[l*8+0]) | (f2bf(dv[l*8+1]) << 16);
        p.y = f2bf(dv[l*8+2]) | (f2bf(dv[l*8+3]) << 16);
        p.z = f2bf(dv[l*8+4]) | (f2bf(dv[l*8+5]) << 16);
        p.w = f2bf(dv[l*8+6]) | (f2bf(dv[l*8+7]) << 16);
        *(uint4*)&abuf[(size_t)g * 512 + (rl + 16 * l) * 8] = p;
    }
    // student-t q: lane j<15 computes cluster j; reduce qs in 16-lane group
    float zz = 0.f;
    #pragma unroll
    for (int k = 0; k < 28; k++) { float zk = zs[wv][k]; zz += zk * zk; }
    float qb = 0.f;
    if (l < 15) {
        float cc = 0.f, zc = 0.f;
        #pragma unroll
        for (int k = 0; k < 28; k++) {
            float cv = cluster[l * 28 + k];
            cc += cv * cv; zc += zs[wv][k] * cv;
        }
        float sq = zz + cc - 2.f * zc;
        if (sq < 0.f) sq = 0.f;
        qb = 1.f / (1.f + sq * (1.f / 0.9f) + 1e-8f);
        qb = powf(qb, 0.95f);
    }
    float qs = qb;
    qs += __shfl_xor(qs, 1); qs += __shfl_xor(qs, 2);
    qs += __shfl_xor(qs, 4); qs += __shfl_xor(qs, 8);
    if (l < 15) out_q[(size_t)d * 15 + l] = qb / qs;
}

// ------------- Kernel I: de_feat = d @ out_w + out_b, MFMA + LDS-staged NT-store epilogue -------------
#define OTS 132   // LDS row stride (132*4B % 16 == 0 -> aligned b128; 2-way write alias = free)
__global__ __launch_bounds__(256) void k_dec_out(
    const unsigned short* __restrict__ abuf, const unsigned short* __restrict__ bfragb,
    const float* __restrict__ ob, float* __restrict__ out_de)
{
    __shared__ float ot[64 * OTS];   // 33.8 KB
    const int tid = threadIdx.x, wid = tid >> 6, l = tid & 63;
    const int gblk = blockIdx.y;               // 64-row block 0..624
    const int ct0 = blockIdx.x * 8;
    frag16 a; a.u = *(const uint4*)&abuf[((size_t)(gblk * 4 + wid)) * 512 + l * 8];
    const int lrow = wid * 16 + (l >> 4) * 4;  // local row base
    const int cl = l & 15;
    #pragma unroll
    for (int c = 0; c < 8; c++) {
        frag16 bfr; bfr.u = *(const uint4*)&bfragb[((size_t)(ct0 + c) * 64 + l) * 8];
        f32x4 acc = {0.f, 0.f, 0.f, 0.f};
        acc = __builtin_amdgcn_mfma_f32_16x16x32_bf16(a.s, bfr.s, acc, 0, 0, 0);
        #pragma unroll
        for (int reg = 0; reg < 4; reg++)
            ot[(lrow + reg) * OTS + c * 16 + cl] = acc[reg];
    }
    __syncthreads();
    const int row0 = gblk * 64;
    const int c0 = ct0 * 16;
    #pragma unroll
    for (int i = 0; i < 8; i++) {
        int idx = i * 256 + tid;
        int r = idx >> 5, q = idx & 31;
        int col = c0 + q * 4;
        if (col < DIN) {
            const float* p = &ot[r * OTS + q * 4];
            float4 bq = *(const float4*)&ob[col];
            f32x4 o;
            o[0] = p[0] + bq.x; o[1] = p[1] + bq.y;
            o[2] = p[2] + bq.z; o[3] = p[3] + bq.w;
            __builtin_nontemporal_store(o, (f32x4*)&out_de[(size_t)(row0 + r) * DIN + col]);
        }
    }
}

extern "C" void kernel_launch(void* const* d_in, const int* in_sizes, int n_in,
                              void* d_out, int out_size, void* d_ws, size_t ws_size,
                              hipStream_t stream) {
    const float* x      = (const float*)d_in[0];
    const int*   ei     = (const int*)  d_in[1];
    const float* e0_w   = (const float*)d_in[2];
    const float* e0_b   = (const float*)d_in[3];
    const float* e0_g   = (const float*)d_in[4];
    const float* e0_be  = (const float*)d_in[5];
    const float* e0_m   = (const float*)d_in[6];
    const float* e0_v   = (const float*)d_in[7];
    const float* e1_w   = (const float*)d_in[8];
    const float* e1_b   = (const float*)d_in[9];
    const float* e1_g   = (const float*)d_in[10];
    const float* e1_be  = (const float*)d_in[11];
    const float* e1_m   = (const float*)d_in[12];
    const float* e1_v   = (const float*)d_in[13];
    const float* g1_w   = (const float*)d_in[14];
    const float* g1_as  = (const float*)d_in[15];
    const float* g1_ad  = (const float*)d_in[16];
    const float* g1_b   = (const float*)d_in[17];
    const float* bnc_g  = (const float*)d_in[18];
    const float* bnc_be = (const float*)d_in[19];
    const float* bnc_m  = (const float*)d_in[20];
    const float* bnc_v  = (const float*)d_in[21];
    const float* gm_w   = (const float*)d_in[22];
    const float* gm_as  = (const float*)d_in[23];
    const float* gm_ad  = (const float*)d_in[24];
    const float* gm_b   = (const float*)d_in[25];
    const float* gv_w   = (const float*)d_in[26];
    const float* gv_as  = (const float*)d_in[27];
    const float* gv_ad  = (const float*)d_in[28];
    const float* gv_b   = (const float*)d_in[29];
    const float* d0_w   = (const float*)d_in[30];
    const float* d0_b   = (const float*)d_in[31];
    const float* d0_g   = (const float*)d_in[32];
    const float* d0_be  = (const float*)d_in[33];
    const float* d0_m   = (const float*)d_in[34];
    const float* d0_v   = (const float*)d_in[35];
    const float* out_w  = (const float*)d_in[36];
    const float* out_b  = (const float*)d_in[37];
    const float* cluster= (const float*)d_in[38];
    const float* epsin  = (const float*)d_in[39];

    float* out = (float*)d_out;
    // output offsets (floats), return order: z, mu, logvar, de_feat, q, feat_x, gnn_z
    float* out_z  = out;
    float* out_mu = out + (size_t)NN * 28;
    float* out_lv = out + (size_t)NN * 36;
    float* out_de = out + (size_t)NN * 44;
    float* out_q  = out + (size_t)NN * 44 + (size_t)NN * DIN;
    float* out_fx = out + (size_t)NN * 59 + (size_t)NN * DIN;
    float* out_gz = out + (size_t)NN * 79 + (size_t)NN * DIN;

    float* ws = (float*)d_ws;
    const size_t n = NN;
    // workspace layout
    unsigned short* hw1b = (unsigned short*)(ws + 64 * n);   // NN*64 bf16 = 64N..96N
    float* s1src   = ws + 96 * n;
    float* s1dst   = ws + 97 * n;
    unsigned short* abuf   = (unsigned short*)(ws + 103 * n);   // NN*32 bf16 = 103N..119N
    unsigned short* bfw    = (unsigned short*)(ws + 119 * n);   // 96*2*512 bf16 (192KB)
    unsigned short* bfragb = (unsigned short*)(ws + 121 * n);   // NCT*64*8 bf16 (192KB)
    // phase-2 (GAT) interleaved buffers (live in region dead during GAT phase)
    float* hwmv = ws;                          // [NN][16] = 0..16N
    float* sv4  = ws + 16 * n;                 // [NN][4]  = 16N..20N

    // bucket CSR lives in the de_feat output region (overwritten last by k_dec_out)
    int* srcs = (int*)out_de;          // NN*64 = 10.24 MB
    int* cnt  = srcs + (size_t)NN * DCAP;  // NN

    const int NB_PREP = (96 * 128 + NCT * 64 + 255) / 256;  // 96

    // bucket fill (1 edge pass, no scan) + weight prep; cnt zeroed via async memset
    (void)hipMemsetAsync(cnt, 0, NN * sizeof(int), stream);
    k_fill_prep<<<NB_E + NB_PREP, 256, 0, stream>>>(ei, cnt, srcs, e0_w, out_w, bfw, bfragb);

    // encoder GEMM + prep fused (h stays in LDS)
    k_enc0_prep<<<NN / 16, 128, 0, stream>>>(x, bfw, e0_b, e0_g, e0_be, e0_m, e0_v,
                                             e1_w, e1_b, e1_g, e1_be, e1_m, e1_v,
                                             g1_w, g1_as, g1_ad,
                                             out_fx, hw1b, s1src, s1dst);
    // GAT1 gather + norm fused (interleaved outputs)
    k_gat1_fused<<<(NN * 64 + 255) / 256, 256, 0, stream>>>(cnt, srcs,
                                                            s1src, s1dst, hw1b,
                                                            g1_b, bnc_g, bnc_be, bnc_m, bnc_v,
                                                            gm_w, gm_as, gm_ad,
                                                            gv_w, gv_as, gv_ad,
                                                            hwmv, sv4);
    // GAT mu/logvar gather + final fused (interleaved gathers)
    k_gat23_final<<<(NN * 64 + 255) / 256, 256, 0, stream>>>(cnt, srcs,
                                                             hwmv, sv4,
                                                             gm_b, gv_b, epsin, out_fx,
                                                             d0_w, d0_b, d0_g, d0_be, d0_m, d0_v,
                                                             cluster,
                                                             out_z, out_mu, out_lv, out_q, out_gz,
                                                             abuf);
    // decoder out (MFMA + coalesced NT-store epilogue)
    dim3 dec_grid(NCT / 8, NN / 64);   // 24 x 625
    k_dec_out<<<dec_grid, 256, 0, stream>>>(abuf, bfragb, out_b, out_de);
}